// Round 9
// baseline (435.598 us; speedup 1.0000x reference)
//
#include <hip/hip_runtime.h>
#include <hip/hip_bf16.h>

// Problem constants
constexpr int kB   = 2;
constexpr int kL   = 96;
constexpr int kH   = 2;
constexpr int kE   = 63;
constexpr int kOUT = 256;
constexpr int kC1  = 64;
constexpr int kC2  = 128;
constexpr int kKS  = 3;
constexpr int kC   = 192;     // E + 1 + CONV2
constexpr int kLT  = 94;      // L - KS + 1
constexpr int kN   = 187;     // 2*LT - 1
constexpr int kTAU = 93;      // distinct signature steps
constexpr int kEV  = 64;
constexpr int kBH  = 4;
constexpr int kSIG = 37056;   // C + C*C = 193*192
constexpr int kNCOL = kBH * kTAU;  // 372 GEMM columns per W

// sigproj: 193 steps of K=192; step-split 32 (7 + 31*6 = 193) -> 512 blocks = 2/CU
constexpr int SPL = 32;

// Workspace layout (floats)
constexpr size_t AUG_OFF  = 0;
constexpr size_t AUG_SZ   = (size_t)2 * kBH * kLT * kC;    // 144384
constexpr size_t D_OFF    = AUG_OFF + AUG_SZ;
constexpr size_t D_SZ     = (size_t)2 * kBH * kTAU * kC;   // 142848
constexpr size_t U_OFF    = D_OFF + D_SZ;
constexpr size_t F_OFF    = U_OFF + D_SZ;
constexpr size_t F_SZ     = (size_t)2 * kBH * kTAU * kOUT; // 190464

typedef __attribute__((ext_vector_type(8))) short short8;
typedef __attribute__((ext_vector_type(4))) float f32x4;

typedef const float __attribute__((address_space(1)))* gptr_t;
typedef float __attribute__((address_space(3)))* lptr_t;

__device__ __forceinline__ unsigned int fbits(float f) { return __float_as_uint(f); }
__device__ __forceinline__ float bitsf(unsigned int u) { return __uint_as_float(u); }

__device__ __forceinline__ unsigned short f2bf(float x) {
    unsigned int u = __float_as_uint(x);
    unsigned int r = (u + 0x7FFFu + ((u >> 16) & 1u)) >> 16;  // RNE
    return (unsigned short)r;
}
__device__ __forceinline__ float bfbits2f(unsigned short u) {
    return bitsf(((unsigned int)u) << 16);
}

union Pack8 { unsigned int u[4]; short8 v; };

// RNE hi/lo split of 8 fp32 -> two bf16x8
__device__ __forceinline__ void split_rne8(float4 x0, float4 x1, short8& hi, short8& lo) {
    float xf[8] = {x0.x, x0.y, x0.z, x0.w, x1.x, x1.y, x1.z, x1.w};
    Pack8 ph, pl;
    #pragma unroll
    for (int p = 0; p < 4; p++) {
        unsigned short ha = f2bf(xf[2 * p]), hb = f2bf(xf[2 * p + 1]);
        ph.u[p] = (unsigned int)ha | ((unsigned int)hb << 16);
        unsigned short la = f2bf(xf[2 * p] - bfbits2f(ha));
        unsigned short lb = f2bf(xf[2 * p + 1] - bfbits2f(hb));
        pl.u[p] = (unsigned int)la | ((unsigned int)lb << 16);
    }
    hi = ph.v; lo = pl.v;
}

// ---------------------------------------------------------------------------
// Kernel A: augment = [trunc(63) | time(1) | relu(conv2(conv1(x)))(128)]
// grid (94 t, 4 bh, 2 qk), 192 threads
// ---------------------------------------------------------------------------
__global__ __launch_bounds__(192) void augment_kernel(
    const float* __restrict__ q, const float* __restrict__ k,
    const float* __restrict__ W1q, const float* __restrict__ b1q,
    const float* __restrict__ W2q, const float* __restrict__ b2q,
    const float* __restrict__ W1k, const float* __restrict__ b1k,
    const float* __restrict__ W2k, const float* __restrict__ b2k,
    float* __restrict__ aug)
{
    const int t  = blockIdx.x;   // 0..93
    const int bh = blockIdx.y;   // 0..3
    const int qk = blockIdx.z;   // 0 = q, 1 = k
    const int tid = threadIdx.x;

    const float* x  = qk ? k   : q;
    const float* W1 = qk ? W1k : W1q;
    const float* b1 = qk ? b1k : b1q;
    const float* W2 = qk ? W2k : W2q;
    const float* b2 = qk ? b2k : b2q;

    __shared__ float xwin[kKS][kE];
    __shared__ float hbuf[kC1];

    const int b = bh >> 1, h = bh & 1;
    if (tid < kKS * kE) {
        int s = tid / kE, e = tid - s * kE;
        xwin[s][e] = x[(((size_t)b * kL + (t + s)) * kH + h) * kE + e];
    }
    __syncthreads();

    if (tid < kC1) {
        float acc = b1[tid];
        const float* wrow = W1 + (size_t)tid * kE * kKS;  // (o1, e, s)
        #pragma unroll 3
        for (int s = 0; s < kKS; s++)
            for (int e = 0; e < kE; e++)
                acc += xwin[s][e] * wrow[e * kKS + s];
        hbuf[tid] = acc;
    }
    __syncthreads();

    float* augrow = aug + ((size_t)(qk * kBH + bh) * kLT + t) * kC;
    if (tid < kC2) {
        float acc = b2[tid];
        const float* wrow = W2 + (size_t)tid * kC1;
        for (int o1 = 0; o1 < kC1; o1++)
            acc += hbuf[o1] * wrow[o1];
        augrow[kE + 1 + tid] = fmaxf(acc, 0.0f);
    }
    if (tid < kE) augrow[tid] = xwin[kKS - 1][tid];   // trunc = x[t+2]
    if (tid == kE) augrow[kE] = (float)t * (1.0f / 93.0f);  // time
}

// ---------------------------------------------------------------------------
// Kernel B: d[tau] = aug[tau+1]-aug[tau]; u[tau] = cumsum(d) - 0.5 d
// grid (4 bh, 2 qk, 3 cgrp), 64 threads (one per channel in group)
// ---------------------------------------------------------------------------
__global__ __launch_bounds__(64) void diffcum_kernel(
    const float* __restrict__ aug, float* __restrict__ dArr, float* __restrict__ uArr)
{
    const int bh = blockIdx.x, qk = blockIdx.y;
    const int c = blockIdx.z * 64 + threadIdx.x;
    const float* a = aug + (size_t)(qk * kBH + bh) * kLT * kC;
    float* dp = dArr + (size_t)(qk * kBH + bh) * kTAU * kC;
    float* up = uArr + (size_t)(qk * kBH + bh) * kTAU * kC;
    float run = 0.f;
    float prev = a[c];
    #pragma unroll 4
    for (int tau = 0; tau < kTAU; tau++) {
        float nxt = a[(size_t)(tau + 1) * kC + c];
        float dd = nxt - prev;
        run += dd;
        dp[(size_t)tau * kC + c] = dd;
        up[(size_t)tau * kC + c] = run - 0.5f * dd;
        prev = nxt;
    }
}

// ---------------------------------------------------------------------------
// Kernel C (MFMA, bilinear, W read-once, split-once, R7-proven serial DMA;
// overlap via 2 blocks/CU):
//   F[qk,n,o] += sum_s scale(s,n) * sum_j W[o, 192 s + j] * d[n, j]
//   Block: 32 o rows x ALL 384 n (8 waves x 48 n), 32-way step split.
//   Per step (3 barriers): DMA 32x192 fp32 W tile -> stage; drain;
//   cooperative RNE split -> bf16 hi/lo LDS; MFMA. u-scales pre-hoisted.
// grid (8 otile, 64 = qk*SPL + is), 512 threads
// ---------------------------------------------------------------------------
__global__ __launch_bounds__(512, 4) void sigproj_kernel(
    const float* __restrict__ Wlq,
    const float* __restrict__ Wlk,
    const float* __restrict__ dArr,
    const float* __restrict__ uArr,
    float* __restrict__ F)
{
    const int otile = blockIdx.x;      // 0..7 -> o rows [otile*32, +32)
    const int zz = blockIdx.y;
    const int qk = zz / SPL;
    const int is = zz - qk * SPL;

    const float* __restrict__ W = qk ? Wlk : Wlq;
    const float* dB = dArr + (size_t)qk * kNCOL * kC;
    const float* uB = uArr + (size_t)qk * kNCOL * kC;

    // fp32 DMA stage: 32 rows, stride 196 words
    __shared__ __align__(16) float stage[32 * 196];
    // bf16 hi/lo: 32 rows, stride 200 shorts (400 B rows, 16B-aligned)
    __shared__ __align__(16) unsigned short WhiS[32 * 200];
    __shared__ __align__(16) unsigned short WloS[32 * 200];

    const int tid  = threadIdx.x;
    const int w    = tid >> 6;      // wave 0..7
    const int lane = tid & 63;
    const int quad = lane >> 4;
    const int l16  = lane & 15;

    // step range: is=0 -> [0,7), else [6*is+1, +6)   (7 + 31*6 = 193)
    const int s0 = (is == 0) ? 0 : 6 * is + 1;
    const int ns = (is == 0) ? 7 : 6;

    // --- B-frags (d) in registers: 3 frags of 16 n, hi/lo RNE split ---
    short8 bh_r[3][6], bl_r[3][6];
    const float* uptr[3];
    float nmask[3];
    #pragma unroll
    for (int f = 0; f < 3; f++) {
        const int n = w * 48 + f * 16 + l16;
        const bool nv = n < kNCOL;
        nmask[f] = nv ? 1.f : 0.f;
        const float* dn = dB + (size_t)(nv ? n : 0) * kC;
        uptr[f] = uB + (size_t)(nv ? n : 0) * kC;
        #pragma unroll
        for (int jb = 0; jb < 6; jb++) {
            float4 x0 = *reinterpret_cast<const float4*>(dn + jb * 32 + quad * 8);
            float4 x1 = *reinterpret_cast<const float4*>(dn + jb * 32 + quad * 8 + 4);
            if (!nv) { x0 = make_float4(0, 0, 0, 0); x1 = make_float4(0, 0, 0, 0); }
            split_rne8(x0, x1, bh_r[f][jb], bl_r[f][jb]);
        }
    }

    // hoist per-step scales out of the serial loop (removes global-load
    // latency from the barrier-serialized path)
    float upre[3][7];
    for (int i = 0; i < ns; i++) {
        const int s = s0 + i;
        #pragma unroll
        for (int f = 0; f < 3; f++)
            upre[f][i] = (s == 0) ? nmask[f] : uptr[f][s - 1] * nmask[f];
    }

    f32x4 acc[2][3];
    #pragma unroll
    for (int a = 0; a < 2; a++)
        #pragma unroll
        for (int f = 0; f < 3; f++)
            acc[a][f] = (f32x4){0.f, 0.f, 0.f, 0.f};

    // DMA: wave w stages rows [w*4, w*4+4); lanes 0..47 carry 16B each
    const int row0 = w * 4;
    const float* gbase = W + (size_t)(otile * 32 + row0) * kSIG + lane * 4;

    for (int ci = 0; ci < ns; ci++) {
        const int s = s0 + ci;

        __syncthreads();   // (a) prev iter's WhiS/WloS + stage consumers done

        if (lane < 48) {
            const float* gp = gbase + (size_t)192 * s;
            #pragma unroll
            for (int i = 0; i < 4; i++)
                __builtin_amdgcn_global_load_lds(
                    (gptr_t)(gp + (size_t)i * kSIG),
                    (lptr_t)&stage[(row0 + i) * 196], 16, 0, 0);
        }
        __syncthreads();   // (b) DMA drained (vmcnt(0) before barrier; proven)

        // --- split-pass: stage fp32 -> bf16 hi/lo (threads 0..383) ---
        if (tid < 384) {
            const int r = tid & 31, cb = tid >> 5;     // row, 16-col block
            const float* src = &stage[r * 196 + cb * 16];
            float4 x0 = *reinterpret_cast<const float4*>(src);
            float4 x1 = *reinterpret_cast<const float4*>(src + 4);
            float4 x2 = *reinterpret_cast<const float4*>(src + 8);
            float4 x3 = *reinterpret_cast<const float4*>(src + 12);
            short8 h0, l0, h1, l1;
            split_rne8(x0, x1, h0, l0);
            split_rne8(x2, x3, h1, l1);
            const int o16 = r * 200 + cb * 16;
            *reinterpret_cast<short8*>(&WhiS[o16]) = h0;
            *reinterpret_cast<short8*>(&WhiS[o16 + 8]) = h1;
            *reinterpret_cast<short8*>(&WloS[o16]) = l0;
            *reinterpret_cast<short8*>(&WloS[o16 + 8]) = l1;
        }
        __syncthreads();   // (c) split visible

        f32x4 tmp[2][3];
        #pragma unroll
        for (int a = 0; a < 2; a++)
            #pragma unroll
            for (int f = 0; f < 3; f++)
                tmp[a][f] = (f32x4){0.f, 0.f, 0.f, 0.f};

        #pragma unroll
        for (int jb = 0; jb < 6; jb++) {
            short8 ah[2], al[2];
            #pragma unroll
            for (int a = 0; a < 2; a++) {
                const int off = (a * 16 + l16) * 200 + jb * 32 + quad * 8;
                ah[a] = *reinterpret_cast<const short8*>(&WhiS[off]);
                al[a] = *reinterpret_cast<const short8*>(&WloS[off]);
            }
            #pragma unroll
            for (int a = 0; a < 2; a++)
                #pragma unroll
                for (int f = 0; f < 3; f++) {
                    tmp[a][f] = __builtin_amdgcn_mfma_f32_16x16x32_bf16(
                        ah[a], bh_r[f][jb], tmp[a][f], 0, 0, 0);
                    tmp[a][f] = __builtin_amdgcn_mfma_f32_16x16x32_bf16(
                        ah[a], bl_r[f][jb], tmp[a][f], 0, 0, 0);
                    tmp[a][f] = __builtin_amdgcn_mfma_f32_16x16x32_bf16(
                        al[a], bh_r[f][jb], tmp[a][f], 0, 0, 0);
                }
        }

        #pragma unroll
        for (int a = 0; a < 2; a++)
            #pragma unroll
            for (int f = 0; f < 3; f++)
                #pragma unroll
                for (int r = 0; r < 4; r++)
                    acc[a][f][r] += upre[f][ci] * tmp[a][f][r];
    }

    // --- epilogue: D row(o) = quad*4 + r, col(n) = l16 (verified R3-R7) ---
    #pragma unroll
    for (int a = 0; a < 2; a++) {
        const int o = otile * 32 + a * 16 + quad * 4;
        #pragma unroll
        for (int f = 0; f < 3; f++) {
            const int n = w * 48 + f * 16 + l16;
            if (n < kNCOL) {
                float* dst = F + ((size_t)qk * kNCOL + n) * kOUT + o;
                #pragma unroll
                for (int r = 0; r < 4; r++)
                    atomicAdd(dst + r, acc[a][f][r]);
            }
        }
    }
}

// ---------------------------------------------------------------------------
// Kernel D: P[qk, bh, tau, o] = bias[o] + cumsum_tau F   (in place)
// grid (4 bh, 2 qk), 256 threads (one per o)
// ---------------------------------------------------------------------------
__global__ __launch_bounds__(256) void cumsum_kernel(
    float* __restrict__ F,
    const float* __restrict__ blq, const float* __restrict__ blk)
{
    const int bh = blockIdx.x, qk = blockIdx.y;
    const int o = threadIdx.x;
    float run = (qk ? blk : blq)[o];
    float* base = F + ((size_t)qk * kNCOL + bh * kTAU) * kOUT + o;
    #pragma unroll 8
    for (int tau = 0; tau < kTAU; tau++) {
        run += base[(size_t)tau * kOUT];
        base[(size_t)tau * kOUT] = run;
    }
}

// fast tanh: 1 - 2/(e^{2x}+1); saturates correctly for |x| large
__device__ __forceinline__ float tanh_fast(float x) {
    return 1.f - 2.f / (__expf(2.f * x) + 1.f);
}

// ---------------------------------------------------------------------------
// Kernel F: A[sg,t] = tanh(QP[sg]·KP[t]); Out = A @ (paired v); scatter dup rows
// grid (93 sigma, 4 bh), 128 threads.
// ---------------------------------------------------------------------------
__global__ __launch_bounds__(128) void attn_kernel(
    const float* __restrict__ P, const float* __restrict__ v,
    float* __restrict__ out)
{
    const int sg = blockIdx.x;   // 0..92
    const int bh = blockIdx.y;   // 0..3
    const int tid = threadIdx.x;

    __shared__ float q_l[kOUT];
    __shared__ __align__(16) float kp_l[kTAU][65];
    __shared__ float A_l[kTAU];

    const float* qrow = P + ((size_t)bh * kTAU + sg) * kOUT;
    q_l[tid] = qrow[tid];
    q_l[tid + 128] = qrow[tid + 128];

    const float* kbase = P + ((size_t)kNCOL + bh * kTAU) * kOUT;
    const int ri = tid >> 6;  // 0..1
    const int oi = tid & 63;
    float dot = 0.f;
    for (int oc = 0; oc < kOUT; oc += 64) {
        __syncthreads();
        for (int t = ri; t < kTAU; t += 2)
            kp_l[t][oi] = kbase[(size_t)t * kOUT + oc + oi];
        __syncthreads();
        if (tid < kTAU) {
            #pragma unroll 8
            for (int i = 0; i < 64; i++)
                dot += q_l[oc + i] * kp_l[tid][i];
        }
    }
    if (tid < kTAU) A_l[tid] = tanh_fast(dot);
    __syncthreads();

    if (tid < kEV) {
        const float* vb = v + (size_t)bh * kN * kEV + tid;
        float acc2 = 0.f;
        #pragma unroll 4
        for (int t = 0; t < kTAU - 1; t++)
            acc2 += A_l[t] * (vb[(size_t)(2 * t) * kEV] + vb[(size_t)(2 * t + 1) * kEV]);
        acc2 += A_l[kTAU - 1] * (vb[(size_t)184 * kEV] + vb[(size_t)185 * kEV] +
                                 vb[(size_t)186 * kEV]);
        const size_t rb = (size_t)bh * kN;
        out[(rb + 2 * sg) * kEV + tid] = acc2;
        out[(rb + 2 * sg + 1) * kEV + tid] = acc2;
        if (sg == kTAU - 1) out[(rb + 186) * kEV + tid] = acc2;
    }
}

// ---------------------------------------------------------------------------
extern "C" void kernel_launch(void* const* d_in, const int* in_sizes, int n_in,
                              void* d_out, int out_size, void* d_ws, size_t ws_size,
                              hipStream_t stream)
{
    (void)in_sizes; (void)n_in; (void)out_size; (void)ws_size;
    auto fp = [&](int i) { return (const float*)d_in[i]; };

    float* ws   = (float*)d_ws;
    float* aug  = ws + AUG_OFF;
    float* dArr = ws + D_OFF;
    float* uArr = ws + U_OFF;
    float* F    = ws + F_OFF;

    hipMemsetAsync(F, 0, F_SZ * sizeof(float), stream);

    augment_kernel<<<dim3(kLT, kBH, 2), 192, 0, stream>>>(
        fp(0), fp(1), fp(3), fp(4), fp(5), fp(6), fp(7), fp(8), fp(9), fp(10), aug);
    diffcum_kernel<<<dim3(kBH, 2, 3), 64, 0, stream>>>(aug, dArr, uArr);
    sigproj_kernel<<<dim3(8, 2 * SPL), 512, 0, stream>>>(
        fp(11), fp(13), dArr, uArr, F);
    cumsum_kernel<<<dim3(kBH, 2), 256, 0, stream>>>(F, fp(12), fp(14));
    attn_kernel<<<dim3(kTAU, kBH), 128, 0, stream>>>(F, fp(2), (float*)d_out);
}

// Round 10
// 312.349 us; speedup vs baseline: 1.3946x; 1.3946x over previous
//
#include <hip/hip_runtime.h>
#include <hip/hip_bf16.h>

// Problem constants
constexpr int kB   = 2;
constexpr int kL   = 96;
constexpr int kH   = 2;
constexpr int kE   = 63;
constexpr int kOUT = 256;
constexpr int kC1  = 64;
constexpr int kC2  = 128;
constexpr int kKS  = 3;
constexpr int kC   = 192;     // E + 1 + CONV2
constexpr int kLT  = 94;      // L - KS + 1
constexpr int kN   = 187;     // 2*LT - 1
constexpr int kTAU = 93;      // distinct signature steps
constexpr int kEV  = 64;
constexpr int kBH  = 4;
constexpr int kSIG = 37056;   // C + C*C = 193*192
constexpr int kNCOL = kBH * kTAU;  // 372 GEMM columns per W

// sigproj: 193 steps of K=192; step-split 32 (7 + 31*6 = 193) -> 512 blocks = 2/CU
constexpr int SPL = 32;

// Workspace layout (floats)
constexpr size_t AUG_OFF  = 0;
constexpr size_t AUG_SZ   = (size_t)2 * kBH * kLT * kC;    // 144384
constexpr size_t D_OFF    = AUG_OFF + AUG_SZ;
constexpr size_t D_SZ     = (size_t)2 * kBH * kTAU * kC;   // 142848
constexpr size_t U_OFF    = D_OFF + D_SZ;
constexpr size_t F_OFF    = U_OFF + D_SZ;
constexpr size_t F_SZ     = (size_t)2 * kBH * kTAU * kOUT; // 190464

typedef __attribute__((ext_vector_type(8))) short short8;
typedef __attribute__((ext_vector_type(4))) float f32x4;

typedef const float __attribute__((address_space(1)))* gptr_t;
typedef float __attribute__((address_space(3)))* lptr_t;

__device__ __forceinline__ unsigned int fbits(float f) { return __float_as_uint(f); }
__device__ __forceinline__ float bitsf(unsigned int u) { return __uint_as_float(u); }

__device__ __forceinline__ unsigned short f2bf(float x) {
    unsigned int u = __float_as_uint(x);
    unsigned int r = (u + 0x7FFFu + ((u >> 16) & 1u)) >> 16;  // RNE
    return (unsigned short)r;
}
__device__ __forceinline__ float bfbits2f(unsigned short u) {
    return bitsf(((unsigned int)u) << 16);
}

union Pack8 { unsigned int u[4]; short8 v; };

// RNE hi/lo split of 8 fp32 -> two bf16x8
__device__ __forceinline__ void split_rne8(float4 x0, float4 x1, short8& hi, short8& lo) {
    float xf[8] = {x0.x, x0.y, x0.z, x0.w, x1.x, x1.y, x1.z, x1.w};
    Pack8 ph, pl;
    #pragma unroll
    for (int p = 0; p < 4; p++) {
        unsigned short ha = f2bf(xf[2 * p]), hb = f2bf(xf[2 * p + 1]);
        ph.u[p] = (unsigned int)ha | ((unsigned int)hb << 16);
        unsigned short la = f2bf(xf[2 * p] - bfbits2f(ha));
        unsigned short lb = f2bf(xf[2 * p + 1] - bfbits2f(hb));
        pl.u[p] = (unsigned int)la | ((unsigned int)lb << 16);
    }
    hi = ph.v; lo = pl.v;
}

// ---------------------------------------------------------------------------
// Kernel A: augment = [trunc(63) | time(1) | relu(conv2(conv1(x)))(128)]
// grid (94 t, 4 bh, 2 qk), 192 threads
// ---------------------------------------------------------------------------
__global__ __launch_bounds__(192) void augment_kernel(
    const float* __restrict__ q, const float* __restrict__ k,
    const float* __restrict__ W1q, const float* __restrict__ b1q,
    const float* __restrict__ W2q, const float* __restrict__ b2q,
    const float* __restrict__ W1k, const float* __restrict__ b1k,
    const float* __restrict__ W2k, const float* __restrict__ b2k,
    float* __restrict__ aug)
{
    const int t  = blockIdx.x;   // 0..93
    const int bh = blockIdx.y;   // 0..3
    const int qk = blockIdx.z;   // 0 = q, 1 = k
    const int tid = threadIdx.x;

    const float* x  = qk ? k   : q;
    const float* W1 = qk ? W1k : W1q;
    const float* b1 = qk ? b1k : b1q;
    const float* W2 = qk ? W2k : W2q;
    const float* b2 = qk ? b2k : b2q;

    __shared__ float xwin[kKS][kE];
    __shared__ float hbuf[kC1];

    const int b = bh >> 1, h = bh & 1;
    if (tid < kKS * kE) {
        int s = tid / kE, e = tid - s * kE;
        xwin[s][e] = x[(((size_t)b * kL + (t + s)) * kH + h) * kE + e];
    }
    __syncthreads();

    if (tid < kC1) {
        float acc = b1[tid];
        const float* wrow = W1 + (size_t)tid * kE * kKS;  // (o1, e, s)
        #pragma unroll 3
        for (int s = 0; s < kKS; s++)
            for (int e = 0; e < kE; e++)
                acc += xwin[s][e] * wrow[e * kKS + s];
        hbuf[tid] = acc;
    }
    __syncthreads();

    float* augrow = aug + ((size_t)(qk * kBH + bh) * kLT + t) * kC;
    if (tid < kC2) {
        float acc = b2[tid];
        const float* wrow = W2 + (size_t)tid * kC1;
        for (int o1 = 0; o1 < kC1; o1++)
            acc += hbuf[o1] * wrow[o1];
        augrow[kE + 1 + tid] = fmaxf(acc, 0.0f);
    }
    if (tid < kE) augrow[tid] = xwin[kKS - 1][tid];   // trunc = x[t+2]
    if (tid == kE) augrow[kE] = (float)t * (1.0f / 93.0f);  // time
}

// ---------------------------------------------------------------------------
// Kernel B: d[tau] = aug[tau+1]-aug[tau]; u[tau] = cumsum(d) - 0.5 d
// grid (4 bh, 2 qk, 3 cgrp), 64 threads (one per channel in group)
// ---------------------------------------------------------------------------
__global__ __launch_bounds__(64) void diffcum_kernel(
    const float* __restrict__ aug, float* __restrict__ dArr, float* __restrict__ uArr)
{
    const int bh = blockIdx.x, qk = blockIdx.y;
    const int c = blockIdx.z * 64 + threadIdx.x;
    const float* a = aug + (size_t)(qk * kBH + bh) * kLT * kC;
    float* dp = dArr + (size_t)(qk * kBH + bh) * kTAU * kC;
    float* up = uArr + (size_t)(qk * kBH + bh) * kTAU * kC;
    float run = 0.f;
    float prev = a[c];
    #pragma unroll 4
    for (int tau = 0; tau < kTAU; tau++) {
        float nxt = a[(size_t)(tau + 1) * kC + c];
        float dd = nxt - prev;
        run += dd;
        dp[(size_t)tau * kC + c] = dd;
        up[(size_t)tau * kC + c] = run - 0.5f * dd;
        prev = nxt;
    }
}

// ---------------------------------------------------------------------------
// Kernel C (MFMA, bilinear, W read-once, split-once, R7-proven serial DMA;
// overlap via 2 co-resident blocks/CU — grid 512, natural VGPR alloc):
//   F[qk,n,o] += sum_s scale(s,n) * sum_j W[o, 192 s + j] * d[n, j]
//   Block: 32 o rows x ALL 384 n (8 waves x 48 n), 32-way step split.
//   Per step (3 barriers): DMA 32x192 fp32 W tile -> stage; drain;
//   cooperative RNE split -> bf16 hi/lo LDS; MFMA.
// grid (8 otile, 64 = qk*SPL + is), 512 threads
// NOTE: plain __launch_bounds__(512) — R7 measured 124 VGPR (4 waves/EU, 2
// blocks/CU feasible). R8's (512,4) capped VGPR=64 -> spills -> 850 MB HBM.
// ---------------------------------------------------------------------------
__global__ __launch_bounds__(512) void sigproj_kernel(
    const float* __restrict__ Wlq,
    const float* __restrict__ Wlk,
    const float* __restrict__ dArr,
    const float* __restrict__ uArr,
    float* __restrict__ F)
{
    const int otile = blockIdx.x;      // 0..7 -> o rows [otile*32, +32)
    const int zz = blockIdx.y;
    const int qk = zz / SPL;
    const int is = zz - qk * SPL;

    const float* __restrict__ W = qk ? Wlk : Wlq;
    const float* dB = dArr + (size_t)qk * kNCOL * kC;
    const float* uB = uArr + (size_t)qk * kNCOL * kC;

    // fp32 DMA stage: 32 rows, stride 196 words
    __shared__ __align__(16) float stage[32 * 196];
    // bf16 hi/lo: 32 rows, stride 200 shorts (400 B rows, 16B-aligned)
    __shared__ __align__(16) unsigned short WhiS[32 * 200];
    __shared__ __align__(16) unsigned short WloS[32 * 200];

    const int tid  = threadIdx.x;
    const int w    = tid >> 6;      // wave 0..7
    const int lane = tid & 63;
    const int quad = lane >> 4;
    const int l16  = lane & 15;

    // step range: is=0 -> [0,7), else [6*is+1, +6)   (7 + 31*6 = 193)
    const int s0 = (is == 0) ? 0 : 6 * is + 1;
    const int ns = (is == 0) ? 7 : 6;

    // --- B-frags (d) in registers: 3 frags of 16 n, hi/lo RNE split ---
    short8 bh_r[3][6], bl_r[3][6];
    const float* uptr[3];
    float nmask[3];
    #pragma unroll
    for (int f = 0; f < 3; f++) {
        const int n = w * 48 + f * 16 + l16;
        const bool nv = n < kNCOL;
        nmask[f] = nv ? 1.f : 0.f;
        const float* dn = dB + (size_t)(nv ? n : 0) * kC;
        uptr[f] = uB + (size_t)(nv ? n : 0) * kC;
        #pragma unroll
        for (int jb = 0; jb < 6; jb++) {
            float4 x0 = *reinterpret_cast<const float4*>(dn + jb * 32 + quad * 8);
            float4 x1 = *reinterpret_cast<const float4*>(dn + jb * 32 + quad * 8 + 4);
            if (!nv) { x0 = make_float4(0, 0, 0, 0); x1 = make_float4(0, 0, 0, 0); }
            split_rne8(x0, x1, bh_r[f][jb], bl_r[f][jb]);
        }
    }

    f32x4 acc[2][3];
    #pragma unroll
    for (int a = 0; a < 2; a++)
        #pragma unroll
        for (int f = 0; f < 3; f++)
            acc[a][f] = (f32x4){0.f, 0.f, 0.f, 0.f};

    // DMA: wave w stages rows [w*4, w*4+4); lanes 0..47 carry 16B each
    const int row0 = w * 4;
    const float* gbase = W + (size_t)(otile * 32 + row0) * kSIG + lane * 4;

    for (int ci = 0; ci < ns; ci++) {
        const int s = s0 + ci;

        __syncthreads();   // (a) prev iter's WhiS/WloS + stage consumers done

        if (lane < 48) {
            const float* gp = gbase + (size_t)192 * s;
            #pragma unroll
            for (int i = 0; i < 4; i++)
                __builtin_amdgcn_global_load_lds(
                    (gptr_t)(gp + (size_t)i * kSIG),
                    (lptr_t)&stage[(row0 + i) * 196], 16, 0, 0);
        }
        __syncthreads();   // (b) DMA drained (vmcnt(0) before barrier; proven)

        // --- split-pass: stage fp32 -> bf16 hi/lo (threads 0..383) ---
        if (tid < 384) {
            const int r = tid & 31, cb = tid >> 5;     // row, 16-col block
            const float* src = &stage[r * 196 + cb * 16];
            float4 x0 = *reinterpret_cast<const float4*>(src);
            float4 x1 = *reinterpret_cast<const float4*>(src + 4);
            float4 x2 = *reinterpret_cast<const float4*>(src + 8);
            float4 x3 = *reinterpret_cast<const float4*>(src + 12);
            short8 h0, l0, h1, l1;
            split_rne8(x0, x1, h0, l0);
            split_rne8(x2, x3, h1, l1);
            const int o16 = r * 200 + cb * 16;
            *reinterpret_cast<short8*>(&WhiS[o16]) = h0;
            *reinterpret_cast<short8*>(&WhiS[o16 + 8]) = h1;
            *reinterpret_cast<short8*>(&WloS[o16]) = l0;
            *reinterpret_cast<short8*>(&WloS[o16 + 8]) = l1;
        }
        __syncthreads();   // (c) split visible

        float uscale[3];
        #pragma unroll
        for (int f = 0; f < 3; f++)
            uscale[f] = (s == 0) ? nmask[f] : uptr[f][s - 1] * nmask[f];

        f32x4 tmp[2][3];
        #pragma unroll
        for (int a = 0; a < 2; a++)
            #pragma unroll
            for (int f = 0; f < 3; f++)
                tmp[a][f] = (f32x4){0.f, 0.f, 0.f, 0.f};

        #pragma unroll
        for (int jb = 0; jb < 6; jb++) {
            short8 ah[2], al[2];
            #pragma unroll
            for (int a = 0; a < 2; a++) {
                const int off = (a * 16 + l16) * 200 + jb * 32 + quad * 8;
                ah[a] = *reinterpret_cast<const short8*>(&WhiS[off]);
                al[a] = *reinterpret_cast<const short8*>(&WloS[off]);
            }
            #pragma unroll
            for (int a = 0; a < 2; a++)
                #pragma unroll
                for (int f = 0; f < 3; f++) {
                    tmp[a][f] = __builtin_amdgcn_mfma_f32_16x16x32_bf16(
                        ah[a], bh_r[f][jb], tmp[a][f], 0, 0, 0);
                    tmp[a][f] = __builtin_amdgcn_mfma_f32_16x16x32_bf16(
                        ah[a], bl_r[f][jb], tmp[a][f], 0, 0, 0);
                    tmp[a][f] = __builtin_amdgcn_mfma_f32_16x16x32_bf16(
                        al[a], bh_r[f][jb], tmp[a][f], 0, 0, 0);
                }
        }

        #pragma unroll
        for (int a = 0; a < 2; a++)
            #pragma unroll
            for (int f = 0; f < 3; f++)
                #pragma unroll
                for (int r = 0; r < 4; r++)
                    acc[a][f][r] += uscale[f] * tmp[a][f][r];
    }

    // --- epilogue: D row(o) = quad*4 + r, col(n) = l16 (verified R3-R7) ---
    #pragma unroll
    for (int a = 0; a < 2; a++) {
        const int o = otile * 32 + a * 16 + quad * 4;
        #pragma unroll
        for (int f = 0; f < 3; f++) {
            const int n = w * 48 + f * 16 + l16;
            if (n < kNCOL) {
                float* dst = F + ((size_t)qk * kNCOL + n) * kOUT + o;
                #pragma unroll
                for (int r = 0; r < 4; r++)
                    atomicAdd(dst + r, acc[a][f][r]);
            }
        }
    }
}

// ---------------------------------------------------------------------------
// Kernel D: P[qk, bh, tau, o] = bias[o] + cumsum_tau F   (in place)
// grid (4 bh, 2 qk), 256 threads (one per o)
// ---------------------------------------------------------------------------
__global__ __launch_bounds__(256) void cumsum_kernel(
    float* __restrict__ F,
    const float* __restrict__ blq, const float* __restrict__ blk)
{
    const int bh = blockIdx.x, qk = blockIdx.y;
    const int o = threadIdx.x;
    float run = (qk ? blk : blq)[o];
    float* base = F + ((size_t)qk * kNCOL + bh * kTAU) * kOUT + o;
    #pragma unroll 8
    for (int tau = 0; tau < kTAU; tau++) {
        run += base[(size_t)tau * kOUT];
        base[(size_t)tau * kOUT] = run;
    }
}

// fast tanh: 1 - 2/(e^{2x}+1); saturates correctly for |x| large
__device__ __forceinline__ float tanh_fast(float x) {
    return 1.f - 2.f / (__expf(2.f * x) + 1.f);
}

// ---------------------------------------------------------------------------
// Kernel F: A[sg,t] = tanh(QP[sg]·KP[t]); Out = A @ (paired v); scatter dup rows
// grid (93 sigma, 4 bh), 128 threads.
// ---------------------------------------------------------------------------
__global__ __launch_bounds__(128) void attn_kernel(
    const float* __restrict__ P, const float* __restrict__ v,
    float* __restrict__ out)
{
    const int sg = blockIdx.x;   // 0..92
    const int bh = blockIdx.y;   // 0..3
    const int tid = threadIdx.x;

    __shared__ float q_l[kOUT];
    __shared__ __align__(16) float kp_l[kTAU][65];
    __shared__ float A_l[kTAU];

    const float* qrow = P + ((size_t)bh * kTAU + sg) * kOUT;
    q_l[tid] = qrow[tid];
    q_l[tid + 128] = qrow[tid + 128];

    const float* kbase = P + ((size_t)kNCOL + bh * kTAU) * kOUT;
    const int ri = tid >> 6;  // 0..1
    const int oi = tid & 63;
    float dot = 0.f;
    for (int oc = 0; oc < kOUT; oc += 64) {
        __syncthreads();
        for (int t = ri; t < kTAU; t += 2)
            kp_l[t][oi] = kbase[(size_t)t * kOUT + oc + oi];
        __syncthreads();
        if (tid < kTAU) {
            #pragma unroll 8
            for (int i = 0; i < 64; i++)
                dot += q_l[oc + i] * kp_l[tid][i];
        }
    }
    if (tid < kTAU) A_l[tid] = tanh_fast(dot);
    __syncthreads();

    if (tid < kEV) {
        const float* vb = v + (size_t)bh * kN * kEV + tid;
        float acc2 = 0.f;
        #pragma unroll 4
        for (int t = 0; t < kTAU - 1; t++)
            acc2 += A_l[t] * (vb[(size_t)(2 * t) * kEV] + vb[(size_t)(2 * t + 1) * kEV]);
        acc2 += A_l[kTAU - 1] * (vb[(size_t)184 * kEV] + vb[(size_t)185 * kEV] +
                                 vb[(size_t)186 * kEV]);
        const size_t rb = (size_t)bh * kN;
        out[(rb + 2 * sg) * kEV + tid] = acc2;
        out[(rb + 2 * sg + 1) * kEV + tid] = acc2;
        if (sg == kTAU - 1) out[(rb + 186) * kEV + tid] = acc2;
    }
}

// ---------------------------------------------------------------------------
extern "C" void kernel_launch(void* const* d_in, const int* in_sizes, int n_in,
                              void* d_out, int out_size, void* d_ws, size_t ws_size,
                              hipStream_t stream)
{
    (void)in_sizes; (void)n_in; (void)out_size; (void)ws_size;
    auto fp = [&](int i) { return (const float*)d_in[i]; };

    float* ws   = (float*)d_ws;
    float* aug  = ws + AUG_OFF;
    float* dArr = ws + D_OFF;
    float* uArr = ws + U_OFF;
    float* F    = ws + F_OFF;

    hipMemsetAsync(F, 0, F_SZ * sizeof(float), stream);

    augment_kernel<<<dim3(kLT, kBH, 2), 192, 0, stream>>>(
        fp(0), fp(1), fp(3), fp(4), fp(5), fp(6), fp(7), fp(8), fp(9), fp(10), aug);
    diffcum_kernel<<<dim3(kBH, 2, 3), 64, 0, stream>>>(aug, dArr, uArr);
    sigproj_kernel<<<dim3(8, 2 * SPL), 512, 0, stream>>>(
        fp(11), fp(13), dArr, uArr, F);
    cumsum_kernel<<<dim3(kBH, 2), 256, 0, stream>>>(F, fp(12), fp(14));
    attn_kernel<<<dim3(kTAU, kBH), 128, 0, stream>>>(F, fp(2), (float*)d_out);
}